// Round 4
// baseline (180.437 us; speedup 1.0000x reference)
//
#include <hip/hip_runtime.h>

constexpr int CH = 128;
constexpr int HH = 48, WW = 48;
constexpr int PP = HH * WW;        // 2304
constexpr int NPIX = 2 * PP;       // 4608
constexpr int K2 = 169;            // 13x13 window

// workspace layout (in floats)
constexpr size_t OFF_XT  = 0;                              // [NPIX][CH] pixel-major x
constexpr size_t OFF_EN  = OFF_XT + (size_t)NPIX * CH;     // [NPIX][CH] enhanced
constexpr size_t OFF_RN  = OFF_EN + (size_t)NPIX * CH;     // [NPIX] 1/max(||x||,eps)
constexpr size_t OFF_DF  = OFF_RN + NPIX;                  // [NPIX] df
constexpr size_t OFF_MM  = OFF_DF + NPIX;                  // [4] uint min/max per batch
constexpr size_t OFF_GN  = OFF_MM + 4;                     // [64*2] mu,rstd
constexpr size_t OFF_GNP = OFF_GN + 128;                   // [72][64] per-block GN partials
constexpr size_t WS_FLOATS = OFF_GNP + 72 * 64;

__device__ __forceinline__ int refl(int t) {
    return t < 0 ? -t : (t > 47 ? 94 - t : t);
}

// ---- transpose x [B,C,H,W] -> xt [B*P][C]; GN partial sums; init minmax --
__global__ __launch_bounds__(256) void k_tr(const float* __restrict__ x,
                                            float* __restrict__ xt,
                                            unsigned* __restrict__ mm,
                                            float* __restrict__ gnp) {
    __shared__ float t[128][65];
    __shared__ float gred[32][8][2];
    const int tid = threadIdx.x;
    const int p0 = blockIdx.x * 64;          // 72 blocks, 64 pixels each
    const int b = p0 / PP, pb = p0 % PP;
    const int pl = tid & 63, cb = tid >> 6;
    const float* xb = x + (size_t)b * CH * PP + pb + pl;
#pragma unroll
    for (int r = 0; r < 32; r++) {
        int c = r * 4 + cb;
        t[c][pl] = xb[(size_t)c * PP];
    }
    __syncthreads();
    {
        const int c4 = tid & 31, pq = tid >> 5;
#pragma unroll
        for (int r = 0; r < 8; r++) {
            int pp = r * 8 + pq;
            float4 v = make_float4(t[c4 * 4][pp], t[c4 * 4 + 1][pp],
                                   t[c4 * 4 + 2][pp], t[c4 * 4 + 3][pp]);
            ((float4*)(xt + ((size_t)(p0 + pp)) * CH))[c4] = v;
        }
    }
    {   // GroupNorm partials: group g = channels 4g..4g+3 over these 64 px
        const int g = tid >> 3, part = tid & 7;
        float s = 0.f, sq = 0.f;
#pragma unroll
        for (int j = 0; j < 8; j++) {
            int px = part * 8 + j;
#pragma unroll
            for (int i = 0; i < 4; i++) {
                float v = t[g * 4 + i][px];
                s += v; sq += v * v;
            }
        }
        gred[g][part][0] = s; gred[g][part][1] = sq;
    }
    __syncthreads();
    if (tid < 64) {
        int g = tid >> 1, which = tid & 1;
        float a = 0.f;
#pragma unroll
        for (int p = 0; p < 8; p++) a += gred[g][p][which];
        gnp[blockIdx.x * 64 + g * 2 + which] = a;
    }
    if (blockIdx.x == 0 && tid < 4) mm[tid] = (tid & 1) ? 0u : 0x7f800000u;
}

// ---- df (inline 2x avg-down + bilinear up + L1), norms, minmax, GN final -
__global__ __launch_bounds__(256) void k_df2(const float* __restrict__ xt,
                                             const float* __restrict__ gnp,
                                             float* __restrict__ df,
                                             float* __restrict__ rn,
                                             unsigned* __restrict__ mm,
                                             float* __restrict__ gnb) {
    __shared__ float dfl[16];
    const int wv = threadIdx.x >> 6, lane = threadIdx.x & 63;
#pragma unroll
    for (int it = 0; it < 4; ++it) {
        const int pl = it * 4 + wv;
        const int pix = blockIdx.x * 16 + pl;   // 288 blocks * 16 px
        const int b = pix / PP, p = pix % PP;
        const int h = p / WW, w = p % WW;
        float py = 0.5f * h - 0.25f; int y0 = (int)floorf(py); float fy = py - (float)y0;
        float px = 0.5f * w - 0.25f; int x0 = (int)floorf(px); float fx = px - (float)x0;
        int y0c = max(y0, 0), y1c = min(y0 + 1, 23);
        int x0c = max(x0, 0), x1c = min(x0 + 1, 23);
        float w00 = (1.f - fy) * (1.f - fx), w01 = (1.f - fy) * fx;
        float w10 = fy * (1.f - fx), w11 = fy * fx;
        // xd(yc,xc) = 0.25 * sum of 4 xt pixels (2yc..2yc+1, 2xc..2xc+1)
        auto ld2 = [&](int yy, int xx) {
            return ((const float2*)(xt + ((size_t)(b * PP + yy * WW + xx)) * CH))[lane];
        };
        auto xd = [&](int yc, int xc) {
            float2 a = ld2(2 * yc, 2 * xc), bq = ld2(2 * yc, 2 * xc + 1);
            float2 c = ld2(2 * yc + 1, 2 * xc), d = ld2(2 * yc + 1, 2 * xc + 1);
            return make_float2(0.25f * (a.x + bq.x + c.x + d.x),
                               0.25f * (a.y + bq.y + c.y + d.y));
        };
        float2 v00 = xd(y0c, x0c), v01 = xd(y0c, x1c);
        float2 v10 = xd(y1c, x0c), v11 = xd(y1c, x1c);
        float2 xv = ((const float2*)(xt + (size_t)pix * CH))[lane];
        float ux = w00 * v00.x + w01 * v01.x + w10 * v10.x + w11 * v11.x;
        float uy = w00 * v00.y + w01 * v01.y + w10 * v10.y + w11 * v11.y;
        float ds = fabsf(xv.x - ux) + fabsf(xv.y - uy);
        float ss = xv.x * xv.x + xv.y * xv.y;
#pragma unroll
        for (int s = 32; s; s >>= 1) { ds += __shfl_xor(ds, s); ss += __shfl_xor(ss, s); }
        if (lane == 0) {
            df[pix] = ds;
            rn[pix] = 1.f / fmaxf(sqrtf(ss), 1e-12f);
            dfl[pl] = ds;
        }
    }
    __syncthreads();
    if (threadIdx.x == 0) {
        float mn = dfl[0], mx = dfl[0];
#pragma unroll
        for (int i = 1; i < 16; i++) { mn = fminf(mn, dfl[i]); mx = fmaxf(mx, dfl[i]); }
        const int b = (blockIdx.x * 16) / PP;   // 16 | 2304, no straddle
        atomicMin(&mm[b * 2], __float_as_uint(mn));
        atomicMax(&mm[b * 2 + 1], __float_as_uint(mx));
    }
    // finalize GroupNorm stats (gnp from k_tr, complete by stream order)
    if (blockIdx.x == 0 && threadIdx.x < 64) {
        const int b = threadIdx.x >> 5;         // tid = b*32+g
        float s = 0.f, sq = 0.f;
        const int g2 = (threadIdx.x & 31) * 2;
#pragma unroll 4
        for (int blk = 0; blk < 36; blk++) {
            int base = (b * 36 + blk) * 64 + g2;
            s += gnp[base]; sq += gnp[base + 1];
        }
        float mu = s / 9216.f;
        float var = sq / 9216.f - mu * mu;
        gnb[threadIdx.x * 2] = mu;
        gnb[threadIdx.x * 2 + 1] = 1.f / sqrtf(var + 1e-5f);
    }
}

// ---- main IPG v4: 2x4 tile, 512 threads (8 waves), channel-split halves --
constexpr int TR = 2, TC = 4;        // tile 2x4 = 8 px
constexpr int RR = TR + 12;          // 14 region rows
constexpr int RC = TC + 12;          // 16 region cols
constexpr int RPX = RR * RC;         // 224 region pixels
constexpr int RST = 20;              // 16 ch + 4 pad (bank-optimal stride)
constexpr int SIMS_W = 176;

__global__ __launch_bounds__(512) void k_main4(const float* __restrict__ xt,
                                               const float* __restrict__ rn,
                                               const float* __restrict__ df,
                                               const unsigned* __restrict__ mm,
                                               const float* __restrict__ gnb,
                                               const float* __restrict__ gamma,
                                               const float* __restrict__ beta,
                                               float* __restrict__ en) {
    __shared__ float region[2][RPX][RST];   // 35.8 KB: [0]=ch chunk i, [1]=chunk i+4
    __shared__ float simsP[2][8][SIMS_W];   // 11.3 KB partial sims per half
    __shared__ int   gaddr[RPX];
    __shared__ float rnr[RPX];

    const int tid = threadIdx.x;
    const int bid = blockIdx.x;             // 576 blocks
    const int b = bid / 288;
    const int t = bid % 288;                // 24 row-tiles x 12 col-tiles
    const int h0 = (t / 12) * TR, w0 = (t % 12) * TC;

    for (int r = tid; r < RPX; r += 512) {
        int ry = r / RC, rx = r % RC;
        int gy = refl(h0 + ry - 6), gx = refl(w0 + rx - 6);
        int pix2 = b * PP + gy * WW + gx;
        gaddr[r] = pix2;
        rnr[r] = rn[pix2];
    }

    const int wv = tid >> 6, lane = tid & 63;
    const int half = wv >> 2, wq = wv & 3;      // half: ch 0-63 vs 64-127
    const int qr = wq >> 1, qc0 = (wq & 1) * 2; // wave owns px (qr,qc0),(qr,qc0+1)

    float acc[4][2];
#pragma unroll
    for (int i = 0; i < 4; i++) { acc[i][0] = 0.f; acc[i][1] = 0.f; }

    // phase 1: 4 iterations; each stages 16-ch chunk for both halves
    for (int it = 0; it < 4; ++it) {
        __syncthreads();                    // prev compute done (and gaddr ready)
#pragma unroll
        for (int g0 = 0; g0 < 4; ++g0) {
            int g = tid + g0 * 512;
            if (g < RPX * 4 * 2) {
                int buf = g >= RPX * 4;
                int gg = g - buf * (RPX * 4);
                int r = gg >> 2, c4 = gg & 3;
                float4 v = *(const float4*)(xt + (size_t)gaddr[r] * CH +
                                            (it + buf * 4) * 16 + c4 * 4);
                *(float4*)&region[buf][r][c4 * 4] = v;
            }
        }
        __syncthreads();
        float ctr[2][16];
#pragma unroll
        for (int d = 0; d < 2; ++d) {
            int rc = (qr + 6) * RC + (qc0 + d + 6);
#pragma unroll
            for (int c4 = 0; c4 < 4; ++c4) {
                float4 v = *(const float4*)&region[half][rc][c4 * 4];
                ctr[d][c4 * 4 + 0] = v.x; ctr[d][c4 * 4 + 1] = v.y;
                ctr[d][c4 * 4 + 2] = v.z; ctr[d][c4 * 4 + 3] = v.w;
            }
        }
#pragma unroll
        for (int rep = 0; rep < 4; ++rep) {
            int r = rep * 64 + lane;
            int rr = r < RPX ? r : 0;
            float rg[16];
#pragma unroll
            for (int c4 = 0; c4 < 4; ++c4) {
                float4 v = *(const float4*)&region[half][rr][c4 * 4];
                rg[c4 * 4 + 0] = v.x; rg[c4 * 4 + 1] = v.y;
                rg[c4 * 4 + 2] = v.z; rg[c4 * 4 + 3] = v.w;
            }
#pragma unroll
            for (int d = 0; d < 2; ++d)
#pragma unroll
                for (int c = 0; c < 16; ++c)
                    acc[rep][d] += rg[c] * ctr[d][c];
        }
    }

    // phase 1.5: write partial dots (no rn scaling yet)
#pragma unroll
    for (int rep = 0; rep < 4; ++rep) {
        int r = rep * 64 + lane;
        if (r < RPX) {
            int rrow = r / RC, rcol = r % RC;
#pragma unroll
            for (int d = 0; d < 2; ++d) {
                int krow = rrow - qr, kcol = rcol - (qc0 + d);
                if ((unsigned)krow < 13u && (unsigned)kcol < 13u) {
                    int q = qr * 4 + qc0 + d;
                    simsP[half][q][krow * 13 + kcol] = acc[rep][d];
                }
            }
        }
    }
    __syncthreads();

    // merge halves + rn scaling
    for (int idx = tid; idx < 8 * K2; idx += 512) {
        int q = idx / K2, k = idx - q * K2;
        int krow = k / 13, kcol = k - krow * 13;
        int qrr = q >> 2, qcc = q & 3;
        int r = (krow + qrr) * RC + kcol + qcc;
        float s = (simsP[0][q][k] + simsP[1][q][k]) * rnr[r] *
                  rnr[(qrr + 6) * RC + qcc + 6];
        simsP[0][q][k] = s;
    }
    __syncthreads();

    // phase 2: wave wv handles tile px q=wv; top-cc extraction + fused gather
    const float dmin = __uint_as_float(mm[b * 2]);
    const float dmax = __uint_as_float(mm[b * 2 + 1]);
    {
        const int q = wv, qrr = q >> 2, qcc = q & 3;
        const int pix = b * PP + (h0 + qrr) * WW + (w0 + qcc);
        float s0 = simsP[0][q][lane];
        float s1 = (64 + lane < K2) ? simsP[0][q][64 + lane] : -1e30f;
        float s2 = (128 + lane < K2) ? simsP[0][q][128 + lane] : -1e30f;
        const float dn = (df[pix] - dmin) / (dmax - dmin + 1e-8f);
        const int cc = 1 + (int)rintf(dn * 15.f);

        float wsum = 0.f, ax = 0.f, ay = 0.f;
        for (int i = 0; i < cc; ++i) {
            float gm = fmaxf(fmaxf(s0, s1), s2);
#pragma unroll
            for (int sft = 1; sft <= 32; sft <<= 1) gm = fmaxf(gm, __shfl_xor(gm, sft));
            unsigned long long m0 = __ballot(s0 == gm);
            unsigned long long m1 = __ballot(s1 == gm);
            unsigned long long m2 = __ballot(s2 == gm);
            int kw = m0 ? (__ffsll(m0) - 1)
                   : m1 ? (64 + __ffsll(m1) - 1)
                        : (128 + __ffsll(m2) - 1);
            bool me = (lane == (kw & 63));
            s0 = (me && kw < 64) ? -1e30f : s0;
            s1 = (me && kw >= 64 && kw < 128) ? -1e30f : s1;
            s2 = (me && kw >= 128) ? -1e30f : s2;
            float wt = expf(gm);
            wsum += wt;
            int krow = kw / 13, kcol = kw - krow * 13;
            int r = (krow + qrr) * RC + kcol + qcc;
            int p2 = gaddr[r];
            float2 v = ((const float2*)(xt + (size_t)p2 * CH))[lane];
            ax += wt * v.x; ay += wt * v.y;
        }
        const float invw = 1.f / wsum;

        float2 xv = ((const float2*)(xt + (size_t)pix * CH))[lane];
        const int c0 = lane * 2;
        const int g = lane >> 1;
        const float mu = gnb[(b * 32 + g) * 2], rstd = gnb[(b * 32 + g) * 2 + 1];
        float e0 = ax * invw + (xv.x - mu) * rstd * gamma[c0] + beta[c0];
        float e1 = ay * invw + (xv.y - mu) * rstd * gamma[c0 + 1] + beta[c0 + 1];
        ((float2*)(en + (size_t)pix * CH))[lane] = make_float2(e0, e1);
    }
}

// ---- FFN v3: e read via wave-uniform global loads (scalarizable) ---------
__global__ __launch_bounds__(256) void k_ffn3(const float* __restrict__ en,
                                              const float* __restrict__ w1,
                                              const float* __restrict__ b1,
                                              const float* __restrict__ w2,
                                              const float* __restrict__ b2,
                                              float* __restrict__ out) {
    __shared__ float hlds[8][256];     // 8 KB
    const int tid = threadIdx.x;
    const int p0 = blockIdx.x * 8;     // 576 blocks, 8 px each (no batch straddle)
    const int b = p0 / PP, pb = p0 % PP;
    const float* ebase = en + (size_t)p0 * CH;
    {   // h[o] for all 8 px; thread = o; e-reads are wave-uniform (s_load/L1)
        const int o = tid;
        float acc[8];
#pragma unroll
        for (int i = 0; i < 8; i++) acc[i] = 0.f;
        const float4* wr = (const float4*)(w1 + (size_t)o * CH);
        for (int c4 = 0; c4 < 32; c4++) {
            float4 wvv = wr[c4];
#pragma unroll
            for (int px = 0; px < 8; px++) {
                float4 ev = *(const float4*)(ebase + (size_t)px * CH + c4 * 4);
                acc[px] += wvv.x * ev.x + wvv.y * ev.y + wvv.z * ev.z + wvv.w * ev.w;
            }
        }
        float bv = b1[o];
#pragma unroll
        for (int px = 0; px < 8; px++) hlds[px][o] = fmaxf(acc[px] + bv, 0.f);
    }
    __syncthreads();
    {   // out = e + w2 @ h + b2; thread = (c, half)
        const int c = tid & 127, hf = tid >> 7;
        const int px0 = hf * 4;
        float acc[4];
#pragma unroll
        for (int i = 0; i < 4; i++) acc[i] = 0.f;
        const float4* wr = (const float4*)(w2 + (size_t)c * 256);
        for (int o4 = 0; o4 < 64; o4++) {
            float4 wvv = wr[o4];
#pragma unroll
            for (int i = 0; i < 4; i++) {
                float4 hv = *(const float4*)&hlds[px0 + i][o4 * 4];  // LDS broadcast
                acc[i] += wvv.x * hv.x + wvv.y * hv.y + wvv.z * hv.z + wvv.w * hv.w;
            }
        }
        float bv = b2[c];
        float* obase = out + ((size_t)(b * CH + c)) * PP + pb + px0;
        float4 v;
        v.x = ebase[(size_t)(px0 + 0) * CH + c] + acc[0] + bv;
        v.y = ebase[(size_t)(px0 + 1) * CH + c] + acc[1] + bv;
        v.z = ebase[(size_t)(px0 + 2) * CH + c] + acc[2] + bv;
        v.w = ebase[(size_t)(px0 + 3) * CH + c] + acc[3] + bv;
        *(float4*)obase = v;
    }
}

extern "C" void kernel_launch(void* const* d_in, const int* in_sizes, int n_in,
                              void* d_out, int out_size, void* d_ws, size_t ws_size,
                              hipStream_t stream) {
    (void)in_sizes; (void)n_in; (void)out_size;
    if (ws_size < WS_FLOATS * sizeof(float)) return;  // would corrupt; fail visibly

    const float* x     = (const float*)d_in[0];
    const float* gamma = (const float*)d_in[1];
    const float* beta  = (const float*)d_in[2];
    const float* w1    = (const float*)d_in[3];
    const float* b1    = (const float*)d_in[4];
    const float* w2    = (const float*)d_in[5];
    const float* b2    = (const float*)d_in[6];
    float* ws = (float*)d_ws;
    float* xt   = ws + OFF_XT;
    float* en   = ws + OFF_EN;
    float* rn   = ws + OFF_RN;
    float* df   = ws + OFF_DF;
    unsigned* mm = (unsigned*)(ws + OFF_MM);
    float* gnb  = ws + OFF_GN;
    float* gnp  = ws + OFF_GNP;
    float* out  = (float*)d_out;

    hipLaunchKernelGGL(k_tr,    dim3(72),  dim3(256), 0, stream, x, xt, mm, gnp);
    hipLaunchKernelGGL(k_df2,   dim3(288), dim3(256), 0, stream, xt, gnp, df, rn, mm, gnb);
    hipLaunchKernelGGL(k_main4, dim3(576), dim3(512), 0, stream, xt, rn, df, mm, gnb, gamma, beta, en);
    hipLaunchKernelGGL(k_ffn3,  dim3(576), dim3(256), 0, stream, en, w1, b1, w2, b2, out);
}

// Round 5
// 83.250 us; speedup vs baseline: 2.1674x; 2.1674x over previous
//
#include <hip/hip_runtime.h>

constexpr int CH = 128;
constexpr int HH = 48, WW = 48;
constexpr int PP = HH * WW;        // 2304
constexpr int NPIX = 2 * PP;       // 4608
constexpr int K2 = 169;            // 13x13 window

// workspace layout (in floats)
constexpr size_t OFF_XT  = 0;                              // [NPIX][CH] pixel-major x
constexpr size_t OFF_EN  = OFF_XT + (size_t)NPIX * CH;     // [NPIX][CH] enhanced
constexpr size_t OFF_RN  = OFF_EN + (size_t)NPIX * CH;     // [NPIX] 1/max(||x||,eps)
constexpr size_t OFF_DF  = OFF_RN + NPIX;                  // [NPIX] df
constexpr size_t OFF_MM  = OFF_DF + NPIX;                  // [4] uint min/max per batch
constexpr size_t OFF_GN  = OFF_MM + 4;                     // [64*2] mu,rstd
constexpr size_t OFF_GNP = OFF_GN + 128;                   // [72][64] per-block GN partials
constexpr size_t WS_FLOATS = OFF_GNP + 72 * 64;

__device__ __forceinline__ int refl(int t) {
    return t < 0 ? -t : (t > 47 ? 94 - t : t);
}

// ---- transpose x [B,C,H,W] -> xt [B*P][C]; GN partial sums; init minmax --
__global__ __launch_bounds__(256) void k_tr(const float* __restrict__ x,
                                            float* __restrict__ xt,
                                            unsigned* __restrict__ mm,
                                            float* __restrict__ gnp) {
    __shared__ float t[128][65];
    __shared__ float gred[32][8][2];
    const int tid = threadIdx.x;
    const int p0 = blockIdx.x * 64;          // 72 blocks, 64 pixels each
    const int b = p0 / PP, pb = p0 % PP;
    const int pl = tid & 63, cb = tid >> 6;
    const float* xb = x + (size_t)b * CH * PP + pb + pl;
#pragma unroll
    for (int r = 0; r < 32; r++) {
        int c = r * 4 + cb;
        t[c][pl] = xb[(size_t)c * PP];
    }
    __syncthreads();
    {
        const int c4 = tid & 31, pq = tid >> 5;
#pragma unroll
        for (int r = 0; r < 8; r++) {
            int pp = r * 8 + pq;
            float4 v = make_float4(t[c4 * 4][pp], t[c4 * 4 + 1][pp],
                                   t[c4 * 4 + 2][pp], t[c4 * 4 + 3][pp]);
            ((float4*)(xt + ((size_t)(p0 + pp)) * CH))[c4] = v;
        }
    }
    {   // GroupNorm partials: group g = channels 4g..4g+3 over these 64 px
        const int g = tid >> 3, part = tid & 7;
        float s = 0.f, sq = 0.f;
#pragma unroll
        for (int j = 0; j < 8; j++) {
            int px = part * 8 + j;
#pragma unroll
            for (int i = 0; i < 4; i++) {
                float v = t[g * 4 + i][px];
                s += v; sq += v * v;
            }
        }
        gred[g][part][0] = s; gred[g][part][1] = sq;
    }
    __syncthreads();
    if (tid < 64) {
        int g = tid >> 1, which = tid & 1;
        float a = 0.f;
#pragma unroll
        for (int p = 0; p < 8; p++) a += gred[g][p][which];
        gnp[blockIdx.x * 64 + g * 2 + which] = a;
    }
    if (blockIdx.x == 0 && tid < 4) mm[tid] = (tid & 1) ? 0u : 0x7f800000u;
}

// ---- df (inline 2x avg-down + bilinear up + L1), norms, minmax, GN final -
__global__ __launch_bounds__(256) void k_df2(const float* __restrict__ xt,
                                             const float* __restrict__ gnp,
                                             float* __restrict__ df,
                                             float* __restrict__ rn,
                                             unsigned* __restrict__ mm,
                                             float* __restrict__ gnb) {
    __shared__ float dfl[16];
    const int wv = threadIdx.x >> 6, lane = threadIdx.x & 63;
#pragma unroll
    for (int it = 0; it < 4; ++it) {
        const int pl = it * 4 + wv;
        const int pix = blockIdx.x * 16 + pl;   // 288 blocks * 16 px
        const int b = pix / PP, p = pix % PP;
        const int h = p / WW, w = p % WW;
        float py = 0.5f * h - 0.25f; int y0 = (int)floorf(py); float fy = py - (float)y0;
        float px = 0.5f * w - 0.25f; int x0 = (int)floorf(px); float fx = px - (float)x0;
        int y0c = max(y0, 0), y1c = min(y0 + 1, 23);
        int x0c = max(x0, 0), x1c = min(x0 + 1, 23);
        float w00 = (1.f - fy) * (1.f - fx), w01 = (1.f - fy) * fx;
        float w10 = fy * (1.f - fx), w11 = fy * fx;
        auto ld2 = [&](int yy, int xx) {
            return ((const float2*)(xt + ((size_t)(b * PP + yy * WW + xx)) * CH))[lane];
        };
        auto xd = [&](int yc, int xc) {
            float2 a = ld2(2 * yc, 2 * xc), bq = ld2(2 * yc, 2 * xc + 1);
            float2 c = ld2(2 * yc + 1, 2 * xc), d = ld2(2 * yc + 1, 2 * xc + 1);
            return make_float2(0.25f * (a.x + bq.x + c.x + d.x),
                               0.25f * (a.y + bq.y + c.y + d.y));
        };
        float2 v00 = xd(y0c, x0c), v01 = xd(y0c, x1c);
        float2 v10 = xd(y1c, x0c), v11 = xd(y1c, x1c);
        float2 xv = ((const float2*)(xt + (size_t)pix * CH))[lane];
        float ux = w00 * v00.x + w01 * v01.x + w10 * v10.x + w11 * v11.x;
        float uy = w00 * v00.y + w01 * v01.y + w10 * v10.y + w11 * v11.y;
        float ds = fabsf(xv.x - ux) + fabsf(xv.y - uy);
        float ss = xv.x * xv.x + xv.y * xv.y;
#pragma unroll
        for (int s = 32; s; s >>= 1) { ds += __shfl_xor(ds, s); ss += __shfl_xor(ss, s); }
        if (lane == 0) {
            df[pix] = ds;
            rn[pix] = 1.f / fmaxf(sqrtf(ss), 1e-12f);
            dfl[pl] = ds;
        }
    }
    __syncthreads();
    if (threadIdx.x == 0) {
        float mn = dfl[0], mx = dfl[0];
#pragma unroll
        for (int i = 1; i < 16; i++) { mn = fminf(mn, dfl[i]); mx = fmaxf(mx, dfl[i]); }
        const int b = (blockIdx.x * 16) / PP;   // 16 | 2304, no straddle
        atomicMin(&mm[b * 2], __float_as_uint(mn));
        atomicMax(&mm[b * 2 + 1], __float_as_uint(mx));
    }
    // finalize GroupNorm stats (gnp from k_tr, complete by stream order)
    if (blockIdx.x == 0 && threadIdx.x < 64) {
        const int b = threadIdx.x >> 5;         // tid = b*32+g
        float s = 0.f, sq = 0.f;
        const int g2 = (threadIdx.x & 31) * 2;
#pragma unroll 4
        for (int blk = 0; blk < 36; blk++) {
            int base = (b * 36 + blk) * 64 + g2;
            s += gnp[base]; sq += gnp[base + 1];
        }
        float mu = s / 9216.f;
        float var = sq / 9216.f - mu * mu;
        gnb[threadIdx.x * 2] = mu;
        gnb[threadIdx.x * 2 + 1] = 1.f / sqrtf(var + 1e-5f);
    }
}

// ---- main IPG v5: 1 pixel per wave, zero barriers, 8-groups-of-8 dots ----
// Wave layout in phase 1: lane = g*8 + cl; group g handles window offset
// kb+g; lane cl owns channels {c*32 + cl*4 .. +4} for c=0..3. One
// global_load_dwordx4 touches 8 dense 128B lines (consecutive k = adjacent
// xt rows) -> coalesced-equivalent. Sims go to wave-private LDS.
__global__ __launch_bounds__(256) void k_main5(const float* __restrict__ xt,
                                               const float* __restrict__ rn,
                                               const float* __restrict__ df,
                                               const unsigned* __restrict__ mm,
                                               const float* __restrict__ gnb,
                                               const float* __restrict__ gamma,
                                               const float* __restrict__ beta,
                                               float* __restrict__ en) {
    __shared__ float sims[4][176];             // 2.8 KB, wave-private rows
    const int tid = threadIdx.x;
    const int wv = tid >> 6, lane = tid & 63;
    const int pix = blockIdx.x * 4 + wv;       // 1152 blocks * 4 px
    const int b = pix / PP, p = pix % PP;
    const int h = p / WW, w = p % WW;
    const int bb = b * PP;
    const int g = lane >> 3, cl = lane & 7;

    // center fragment: ctr[c] = xt[pix][c*32 + cl*4 ..+4)
    float4 ctr[4];
    const float4* cp = (const float4*)(xt + (size_t)pix * CH) + cl;
#pragma unroll
    for (int c = 0; c < 4; c++) ctr[c] = cp[c * 8];
    const float rnp = rn[pix];

    // phase 1: 22 batches x 8 offsets; no barriers (same-wave LDS use)
    for (int kb = 0; kb < 176; kb += 8) {
        const int k = kb + g;
        const int krow = k / 13, kcol = k - krow * 13;
        const int yy = refl(h + krow - 6), xx = refl(w + kcol - 6);
        const int p2 = bb + yy * WW + xx;
        const float4* rp = (const float4*)(xt + (size_t)p2 * CH) + cl;
        float dot = 0.f;
#pragma unroll
        for (int c = 0; c < 4; c++) {
            float4 v = rp[c * 8];
            dot += v.x * ctr[c].x + v.y * ctr[c].y + v.z * ctr[c].z + v.w * ctr[c].w;
        }
        dot += __shfl_xor(dot, 1);
        dot += __shfl_xor(dot, 2);
        dot += __shfl_xor(dot, 4);
        float s = dot * rnp * rn[p2];
        if (cl == 0 && k < K2) sims[wv][k] = s;
    }

    // phase 2: top-cc extraction (value desc, index asc) + fused gather
    float s0 = sims[wv][lane];
    float s1 = (64 + lane < K2) ? sims[wv][64 + lane] : -1e30f;
    float s2 = (128 + lane < K2) ? sims[wv][128 + lane] : -1e30f;
    const float dmin = __uint_as_float(mm[b * 2]);
    const float dmax = __uint_as_float(mm[b * 2 + 1]);
    const float dn = (df[pix] - dmin) / (dmax - dmin + 1e-8f);
    const int cc = 1 + (int)rintf(dn * 15.f);

    float wsum = 0.f, ax = 0.f, ay = 0.f;
    for (int i = 0; i < cc; ++i) {
        float gm = fmaxf(fmaxf(s0, s1), s2);
#pragma unroll
        for (int sft = 1; sft <= 32; sft <<= 1) gm = fmaxf(gm, __shfl_xor(gm, sft));
        unsigned long long m0 = __ballot(s0 == gm);
        unsigned long long m1 = __ballot(s1 == gm);
        unsigned long long m2 = __ballot(s2 == gm);
        int kw = m0 ? (__ffsll(m0) - 1)
               : m1 ? (64 + __ffsll(m1) - 1)
                    : (128 + __ffsll(m2) - 1);
        bool me = (lane == (kw & 63));
        s0 = (me && kw < 64) ? -1e30f : s0;
        s1 = (me && kw >= 64 && kw < 128) ? -1e30f : s1;
        s2 = (me && kw >= 128) ? -1e30f : s2;
        float wt = expf(gm);
        wsum += wt;
        int krow = kw / 13, kcol = kw - krow * 13;
        int p2 = bb + refl(h + krow - 6) * WW + refl(w + kcol - 6);
        float2 v = ((const float2*)(xt + (size_t)p2 * CH))[lane];
        ax += wt * v.x; ay += wt * v.y;
    }
    const float invw = 1.f / wsum;

    // GroupNorm + residual
    float2 xv = ((const float2*)(xt + (size_t)pix * CH))[lane];
    const int c0 = lane * 2;
    const int grp = lane >> 1;
    const float mu = gnb[(b * 32 + grp) * 2], rstd = gnb[(b * 32 + grp) * 2 + 1];
    float e0 = ax * invw + (xv.x - mu) * rstd * gamma[c0] + beta[c0];
    float e1 = ay * invw + (xv.y - mu) * rstd * gamma[c0 + 1] + beta[c0 + 1];
    ((float2*)(en + (size_t)pix * CH))[lane] = make_float2(e0, e1);
}

// ---- FFN: e read via wave-uniform global loads (scalarizable) ------------
__global__ __launch_bounds__(256) void k_ffn3(const float* __restrict__ en,
                                              const float* __restrict__ w1,
                                              const float* __restrict__ b1,
                                              const float* __restrict__ w2,
                                              const float* __restrict__ b2,
                                              float* __restrict__ out) {
    __shared__ float hlds[8][256];     // 8 KB
    const int tid = threadIdx.x;
    const int p0 = blockIdx.x * 8;     // 576 blocks, 8 px each (no batch straddle)
    const int b = p0 / PP, pb = p0 % PP;
    const float* ebase = en + (size_t)p0 * CH;
    {   // h[o] for all 8 px; thread = o; e-reads are wave-uniform (s_load/L1)
        const int o = tid;
        float acc[8];
#pragma unroll
        for (int i = 0; i < 8; i++) acc[i] = 0.f;
        const float4* wr = (const float4*)(w1 + (size_t)o * CH);
        for (int c4 = 0; c4 < 32; c4++) {
            float4 wvv = wr[c4];
#pragma unroll
            for (int px = 0; px < 8; px++) {
                float4 ev = *(const float4*)(ebase + (size_t)px * CH + c4 * 4);
                acc[px] += wvv.x * ev.x + wvv.y * ev.y + wvv.z * ev.z + wvv.w * ev.w;
            }
        }
        float bv = b1[o];
#pragma unroll
        for (int px = 0; px < 8; px++) hlds[px][o] = fmaxf(acc[px] + bv, 0.f);
    }
    __syncthreads();
    {   // out = e + w2 @ h + b2; thread = (c, half)
        const int c = tid & 127, hf = tid >> 7;
        const int px0 = hf * 4;
        float acc[4];
#pragma unroll
        for (int i = 0; i < 4; i++) acc[i] = 0.f;
        const float4* wr = (const float4*)(w2 + (size_t)c * 256);
        for (int o4 = 0; o4 < 64; o4++) {
            float4 wvv = wr[o4];
#pragma unroll
            for (int i = 0; i < 4; i++) {
                float4 hv = *(const float4*)&hlds[px0 + i][o4 * 4];  // LDS broadcast
                acc[i] += wvv.x * hv.x + wvv.y * hv.y + wvv.z * hv.z + wvv.w * hv.w;
            }
        }
        float bv = b2[c];
        float* obase = out + ((size_t)(b * CH + c)) * PP + pb + px0;
        float4 v;
        v.x = ebase[(size_t)(px0 + 0) * CH + c] + acc[0] + bv;
        v.y = ebase[(size_t)(px0 + 1) * CH + c] + acc[1] + bv;
        v.z = ebase[(size_t)(px0 + 2) * CH + c] + acc[2] + bv;
        v.w = ebase[(size_t)(px0 + 3) * CH + c] + acc[3] + bv;
        *(float4*)obase = v;
    }
}

extern "C" void kernel_launch(void* const* d_in, const int* in_sizes, int n_in,
                              void* d_out, int out_size, void* d_ws, size_t ws_size,
                              hipStream_t stream) {
    (void)in_sizes; (void)n_in; (void)out_size;
    if (ws_size < WS_FLOATS * sizeof(float)) return;  // would corrupt; fail visibly

    const float* x     = (const float*)d_in[0];
    const float* gamma = (const float*)d_in[1];
    const float* beta  = (const float*)d_in[2];
    const float* w1    = (const float*)d_in[3];
    const float* b1    = (const float*)d_in[4];
    const float* w2    = (const float*)d_in[5];
    const float* b2    = (const float*)d_in[6];
    float* ws = (float*)d_ws;
    float* xt   = ws + OFF_XT;
    float* en   = ws + OFF_EN;
    float* rn   = ws + OFF_RN;
    float* df   = ws + OFF_DF;
    unsigned* mm = (unsigned*)(ws + OFF_MM);
    float* gnb  = ws + OFF_GN;
    float* gnp  = ws + OFF_GNP;
    float* out  = (float*)d_out;

    hipLaunchKernelGGL(k_tr,    dim3(72),   dim3(256), 0, stream, x, xt, mm, gnp);
    hipLaunchKernelGGL(k_df2,   dim3(288),  dim3(256), 0, stream, xt, gnp, df, rn, mm, gnb);
    hipLaunchKernelGGL(k_main5, dim3(1152), dim3(256), 0, stream, xt, rn, df, mm, gnb, gamma, beta, en);
    hipLaunchKernelGGL(k_ffn3,  dim3(576),  dim3(256), 0, stream, en, w1, b1, w2, b2, out);
}